// Round 5
// baseline (777.428 us; speedup 1.0000x reference)
//
#include <hip/hip_runtime.h>
#include <hip/hip_fp16.h>
#include <math.h>

#define B_SZ 64
#define T_SZ 512
#define E_SZ 300
#define M_TOT (B_SZ * T_SZ)   // 32768 tokens
#define HSTR  152             // row stride (uints) of packed-f16x2 buffers (304 halves)

typedef _Float16 f16x8 __attribute__((ext_vector_type(8)));
typedef float    f32x4 __attribute__((ext_vector_type(4)));
typedef _Float16 h2_t  __attribute__((ext_vector_type(2)));

// f16-pair dot with fp32 accumulate
__device__ __forceinline__ float dot2(unsigned int a, unsigned int b, float c) {
#if __has_builtin(__builtin_amdgcn_fdot2)
    h2_t ah = __builtin_bit_cast(h2_t, a);
    h2_t bh = __builtin_bit_cast(h2_t, b);
    return __builtin_amdgcn_fdot2(ah, bh, c, false);
#else
    __half2 ah = __builtin_bit_cast(__half2, a);
    __half2 bh = __builtin_bit_cast(__half2, b);
    return c + __low2float(ah) * __low2float(bh) + __high2float(ah) * __high2float(bh);
#endif
}

__device__ __forceinline__ unsigned int packrte(float a, float b) {
    __half2 h = __floats2half2_rn(a, b);
    return __builtin_bit_cast(unsigned int, h);
}

// =====================================================================
// W fp32 -> packed f16x2, K padded to 320 halves (160 uints), zero tail.
// grid (300, 3), 160 threads. Wh layout: [mat][300][160 uints]
// =====================================================================
__global__ __launch_bounds__(160) void wconv(
    const float* __restrict__ fc1_w, const float* __restrict__ l1_w,
    const float* __restrict__ l2_w, unsigned int* __restrict__ Wh)
{
    const int r = blockIdx.x, m = blockIdx.y, j = threadIdx.x;
    const float* src; int stride;
    if (m == 0)      { src = fc1_w; stride = 300; }
    else if (m == 1) { src = l1_w;  stride = 600; }   // x-part cols 0..299
    else             { src = l2_w;  stride = 300; }
    int k = 2 * j;
    float a = (k < 300) ? src[(long)r * stride + k]     : 0.f;
    float b = (k < 300) ? src[(long)r * stride + k + 1] : 0.f;  // 300 even
    Wh[((long)m * 300 + r) * 160 + j] = packrte(a, b);
}

// =====================================================================
// MFMA GEMM: C[M,300] = A[M,300] @ W.T + bias  (f16 inputs, fp32 acc)
// Block tile 64(M) x 160(N), K-chunks of 32 (10 chunks, K padded to 320).
// 256 threads = 4 waves; wave w owns rows 16w..16w+15, all 10 n-frags.
// GATHER: A row m = emb[idx[m]] fp32 (convert in staging).
// else:   A = packed f16 [M][152 uints].
// OMODE: 0 = +bias, fp32 store;  1 = +bias, relu, f16 store (+pad zeros);
//        2 = +bias, max over 64 rows -> part[bx*320 + n]
// =====================================================================
template<bool GATHER, int OMODE>
__global__ __launch_bounds__(256) void mfma_gemm(
    const float* __restrict__ embA, const unsigned int* __restrict__ Ah,
    const int* __restrict__ idx,
    const unsigned int* __restrict__ Wh,   // [300][160] packed f16x2
    const float* __restrict__ bias,
    float* __restrict__ Cf, __half* __restrict__ Chh)
{
    __shared__ _Float16 At[64 * 40];    // row stride 40 halves (80 B)
    __shared__ _Float16 Bt[160 * 40];
    __shared__ float red[4][160];

    const int tid  = threadIdx.x;
    const int m0   = blockIdx.x * 64;
    const int n0   = blockIdx.y * 160;
    const int w    = tid >> 6;
    const int lane = tid & 63;
    const int ml   = lane & 15;
    const int q    = lane >> 4;

    const int ar = tid >> 2, ap = tid & 3;
    const float*        embrow = nullptr;
    const unsigned int* arow   = nullptr;
    if (GATHER) embrow = embA + (long)idx[m0 + ar] * 300;
    else        arow   = Ah + (long)(m0 + ar) * HSTR;

    f32x4 acc[10];
    #pragma unroll
    for (int i = 0; i < 10; i++) acc[i] = (f32x4){0.f, 0.f, 0.f, 0.f};

    #pragma unroll 1
    for (int kc = 0; kc < 10; kc++) {
        uint4 aval;
        if (GATHER) {
            int k = kc * 32 + ap * 8;
            float4 f0 = (k < 300)     ? *(const float4*)(embrow + k)     : make_float4(0,0,0,0);
            float4 f1 = (k + 4 < 300) ? *(const float4*)(embrow + k + 4) : make_float4(0,0,0,0);
            aval = make_uint4(packrte(f0.x, f0.y), packrte(f0.z, f0.w),
                              packrte(f1.x, f1.y), packrte(f1.z, f1.w));
        } else {
            int u = kc * 16 + ap * 4;
            aval = (u <= 148) ? *(const uint4*)(arow + u) : make_uint4(0, 0, 0, 0);
        }
        uint4 bval[3];
        #pragma unroll
        for (int jj = 0; jj < 3; jj++) {
            int i = tid + jj * 256;
            if (i < 640) {
                int row = i >> 2, quad = i & 3;
                int n = n0 + row;
                bval[jj] = (n < 300)
                    ? *(const uint4*)(Wh + (long)n * 160 + kc * 16 + quad * 4)
                    : make_uint4(0, 0, 0, 0);
            }
        }
        __syncthreads();
        *(uint4*)&At[ar * 40 + ap * 8] = aval;
        #pragma unroll
        for (int jj = 0; jj < 3; jj++) {
            int i = tid + jj * 256;
            if (i < 640) {
                int row = i >> 2, quad = i & 3;
                *(uint4*)&Bt[row * 40 + quad * 8] = bval[jj];
            }
        }
        __syncthreads();

        f16x8 af = *(const f16x8*)&At[(16 * w + ml) * 40 + q * 8];
        #pragma unroll
        for (int fi = 0; fi < 10; fi++) {
            f16x8 bf = *(const f16x8*)&Bt[(fi * 16 + ml) * 40 + q * 8];
            acc[fi] = __builtin_amdgcn_mfma_f32_16x16x32_f16(af, bf, acc[fi], 0, 0, 0);
        }
    }

    if (OMODE == 0 || OMODE == 1) {
        #pragma unroll
        for (int fi = 0; fi < 10; fi++) {
            int col = n0 + fi * 16 + ml;
            float bv = (col < 300) ? bias[col] : 0.f;
            #pragma unroll
            for (int r = 0; r < 4; r++) {
                long m = m0 + 16 * w + q * 4 + r;
                float v = acc[fi][r] + bv;
                if (OMODE == 0) {
                    if (col < 300) Cf[m * 300 + col] = v;
                } else {
                    if (col < 300)      Chh[m * 304 + col] = __float2half_rn(fmaxf(v, 0.f));
                    else if (col < 304) Chh[m * 304 + col] = __float2half_rn(0.f);
                }
            }
        }
    } else {
        #pragma unroll
        for (int fi = 0; fi < 10; fi++) {
            float v = fmaxf(fmaxf(acc[fi][0], acc[fi][1]), fmaxf(acc[fi][2], acc[fi][3]));
            v = fmaxf(v, __shfl_xor(v, 16));
            v = fmaxf(v, __shfl_xor(v, 32));
            if (lane < 16) red[w][fi * 16 + lane] = v;
        }
        __syncthreads();
        if (tid < 160) {
            int col = n0 + tid;
            if (col < 300) {
                float v = fmaxf(fmaxf(red[0][tid], red[1][tid]),
                                fmaxf(red[2][tid], red[3][tid]));
                Cf[(long)blockIdx.x * 320 + col] = v + bias[col];
            }
        }
    }
}

// =====================================================================
// RNN v5: one block (512 thr, 8 waves) per batch element. ONE barrier/step.
// Lane layout: wave w, lane l: active if l<60; group g = 10w + l/6 (0..74),
// slice s = l%6. Thread owns outputs 4g..4g+3 over k-halves [50s,50s+50):
// 100 weight uints in regs. k-reduction via shfl (xor1, down2, down4) --
// the 6 slice partners are adjacent lanes. h double-buffered in LDS
// (slice-padded layout, stride 28 uints) -> single barrier per step.
// Lead lane (s==0) does sigmoid, writes h pair-uints, stashes output,
// flushes to global every 8 steps.
// =====================================================================
__global__ __launch_bounds__(512) void rnn_v5(
    const float* __restrict__ xpart,        // [B, T, 300] fp32
    const float* __restrict__ l1_w,         // [300, 600] fp32
    unsigned int* __restrict__ hid_out)     // [B, T, HSTR] packed f16x2
{
    const int b   = blockIdx.x;
    const int tid = threadIdx.x;
    const int w   = tid >> 6;
    const int l   = tid & 63;
    const int g   = w * 10 + l / 6;     // 0..74 (when active)
    const int s   = l % 6;              // 0..5
    const bool act  = (l < 60) && (g < 75);
    const bool lead = act && (s == 0);

    __shared__ unsigned int hb[2][6 * 28];   // double-buffered h, slice stride 28

    // ---- weight preload: wq[o][i] = pack(W[4g+o][300+50s+2i], +2i+1)
    unsigned int wq[4][25];
    if (act) {
        #pragma unroll
        for (int o = 0; o < 4; o++) {
            const float2* wr = (const float2*)(l1_w + (long)(4 * g + o) * 600 + 300 + 50 * s);
            #pragma unroll
            for (int i = 0; i < 25; i++) {
                float2 f = wr[i];
                wq[o][i] = packrte(f.x, f.y);
            }
        }
    }

    const long xb = (long)b * T_SZ * 300;
    unsigned int* gout = hid_out + (long)b * T_SZ * HSTR;

    float4 xp = make_float4(0.f, 0.f, 0.f, 0.f);
    if (lead) xp = *(const float4*)(xpart + xb + 4 * g);   // t=0

    if (tid < 336) ((unsigned int*)hb)[tid] = 0u;          // h0 = 0 (both bufs)
    __syncthreads();

    uint2 hreg[8];

    #pragma unroll 1
    for (int t = 0; t < T_SZ; t++) {
        // prefetch next step's additive term (drained at step-end barrier)
        float4 xpn = xp;
        if (lead) {
            int tn = (t + 1 < T_SZ) ? t + 1 : t;
            xpn = *(const float4*)(xpart + xb + (long)tn * 300 + 4 * g);
        }

        float a0 = 0.f, a1 = 0.f, a2 = 0.f, a3 = 0.f;
        if (act) {
            const unsigned int* hbase = &hb[t & 1][28 * s];
            const uint4* hv = (const uint4*)hbase;
            #pragma unroll
            for (int i = 0; i < 6; i++) {
                uint4 h4 = hv[i];
                a0 = dot2(wq[0][4 * i + 0], h4.x, a0);
                a1 = dot2(wq[1][4 * i + 0], h4.x, a1);
                a2 = dot2(wq[2][4 * i + 0], h4.x, a2);
                a3 = dot2(wq[3][4 * i + 0], h4.x, a3);
                a0 = dot2(wq[0][4 * i + 1], h4.y, a0);
                a1 = dot2(wq[1][4 * i + 1], h4.y, a1);
                a2 = dot2(wq[2][4 * i + 1], h4.y, a2);
                a3 = dot2(wq[3][4 * i + 1], h4.y, a3);
                a0 = dot2(wq[0][4 * i + 2], h4.z, a0);
                a1 = dot2(wq[1][4 * i + 2], h4.z, a1);
                a2 = dot2(wq[2][4 * i + 2], h4.z, a2);
                a3 = dot2(wq[3][4 * i + 2], h4.z, a3);
                a0 = dot2(wq[0][4 * i + 3], h4.w, a0);
                a1 = dot2(wq[1][4 * i + 3], h4.w, a1);
                a2 = dot2(wq[2][4 * i + 3], h4.w, a2);
                a3 = dot2(wq[3][4 * i + 3], h4.w, a3);
            }
            unsigned int tail = hbase[24];
            a0 = dot2(wq[0][24], tail, a0);
            a1 = dot2(wq[1][24], tail, a1);
            a2 = dot2(wq[2][24], tail, a2);
            a3 = dot2(wq[3][24], tail, a3);
        }

        // ---- k-reduce across the 6 slice lanes (adjacent): xor1, down2, down4
        a0 += __shfl_xor(a0, 1);
        a1 += __shfl_xor(a1, 1);
        a2 += __shfl_xor(a2, 1);
        a3 += __shfl_xor(a3, 1);
        {
            float u0 = __shfl_down(a0, 2), v0 = __shfl_down(a0, 4);
            float u1 = __shfl_down(a1, 2), v1 = __shfl_down(a1, 4);
            float u2 = __shfl_down(a2, 2), v2 = __shfl_down(a2, 4);
            float u3 = __shfl_down(a3, 2), v3 = __shfl_down(a3, 4);
            a0 += u0 + v0;  a1 += u1 + v1;  a2 += u2 + v2;  a3 += u3 + v3;
        }

        if (lead) {
            float y0 = xp.x + a0, y1 = xp.y + a1, y2 = xp.z + a2, y3 = xp.w + a3;
            float h0 = 1.f / (1.f + __expf(-y0));
            float h1 = 1.f / (1.f + __expf(-y1));
            float h2 = 1.f / (1.f + __expf(-y2));
            float h3 = 1.f / (1.f + __expf(-y3));
            unsigned int pk0 = packrte(h0, h1);
            unsigned int pk1 = packrte(h2, h3);
            // write into next-step buffer, slice-padded layout
            unsigned int* nb = hb[(t + 1) & 1];
            int p0 = 2 * g, p1 = 2 * g + 1;
            nb[(p0 / 25) * 28 + p0 % 25] = pk0;
            nb[(p1 / 25) * 28 + p1 % 25] = pk1;
            hreg[t & 7] = make_uint2(pk0, pk1);
            if ((t & 7) == 7) {
                #pragma unroll
                for (int st = 0; st < 8; st++)
                    *(uint2*)&gout[(long)(t - 7 + st) * HSTR + 2 * g] = hreg[st];
            }
        }
        xp = xpn;
        __syncthreads();
    }
}

// =====================================================================
// Final: pooled[b,n] = max over 8 m-chunks of part; out = pooled @ fc2_w.T
// =====================================================================
__global__ __launch_bounds__(320) void fc2_final(
    const float* __restrict__ part,     // [512, 320]
    const float* __restrict__ fc2_w,
    const float* __restrict__ fc2_b,
    float* __restrict__ out)
{
    const int b   = blockIdx.x;
    const int tid = threadIdx.x;
    __shared__ float pooled[304];

    if (tid < 300) {
        float m = part[(long)(b * 8) * 320 + tid];
        #pragma unroll
        for (int c = 1; c < 8; c++)
            m = fmaxf(m, part[(long)(b * 8 + c) * 320 + tid]);
        pooled[tid] = m;
    }
    __syncthreads();

    const int o    = tid >> 6;
    const int lane = tid & 63;
    if (o < 2) {
        float sacc = 0.f;
        for (int jj = lane; jj < 300; jj += 64)
            sacc += pooled[jj] * fc2_w[o * 300 + jj];
        #pragma unroll
        for (int off = 32; off > 0; off >>= 1)
            sacc += __shfl_down(sacc, off);
        if (lane == 0) out[b * 2 + o] = sacc + fc2_b[o];
    }
}

// =====================================================================
extern "C" void kernel_launch(void* const* d_in, const int* in_sizes, int n_in,
                              void* d_out, int out_size, void* d_ws, size_t ws_size,
                              hipStream_t stream)
{
    const int*   x     = (const int*)  d_in[0];
    const float* emb   = (const float*)d_in[1];
    const float* fc1_w = (const float*)d_in[2];
    const float* fc1_b = (const float*)d_in[3];
    const float* l1_w  = (const float*)d_in[4];
    const float* l1_b  = (const float*)d_in[5];
    const float* l2_w  = (const float*)d_in[6];
    const float* l2_b  = (const float*)d_in[7];
    const float* fc2_w = (const float*)d_in[8];
    const float* fc2_b = (const float*)d_in[9];
    float* out = (float*)d_out;

    // ws layout: bufH (19.9 MB) | bufX (39.3 MB) | part (0.66 MB) | Wh (0.58 MB)
    unsigned int* bufH = (unsigned int*)d_ws;
    float* bufX = (float*)(bufH + (size_t)M_TOT * HSTR);
    float* part = bufX + (size_t)M_TOT * 300;
    unsigned int* WhAll = (unsigned int*)(part + (size_t)512 * 320);
    unsigned int* W1h = WhAll;
    unsigned int* W2h = WhAll + (size_t)300 * 160;
    unsigned int* W3h = WhAll + (size_t)2 * 300 * 160;

    // K0: weights fp32 -> f16, K padded to 320
    wconv<<<dim3(300, 3), 160, 0, stream>>>(fc1_w, l1_w, l2_w, WhAll);
    // K1: h = relu(emb[x] @ fc1_w.T + fc1_b) -> packed f16 (pads zeroed)
    mfma_gemm<true, 1><<<dim3(512, 2), 256, 0, stream>>>(
        emb, nullptr, x, W1h, fc1_b, nullptr, (__half*)bufH);
    // K2: xpart = h @ l1_w[:, :300].T + l1_b -> fp32
    mfma_gemm<false, 0><<<dim3(512, 2), 256, 0, stream>>>(
        nullptr, bufH, nullptr, W2h, l1_b, bufX, nullptr);
    // K3: sequential RNN -> packed hiddens (overwrites bufH)
    rnn_v5<<<B_SZ, 512, 0, stream>>>(bufX, l1_w, bufH);
    // K4: outs = hid @ l2_w.T + l2_b, fused 64-row max -> part
    mfma_gemm<false, 2><<<dim3(512, 2), 256, 0, stream>>>(
        nullptr, bufH, nullptr, W3h, l2_b, part, nullptr);
    // K5: final max over chunks + fc2
    fc2_final<<<B_SZ, 320, 0, stream>>>(part, fc2_w, fc2_b, out);
}

// Round 6
// 603.618 us; speedup vs baseline: 1.2879x; 1.2879x over previous
//
#include <hip/hip_runtime.h>
#include <hip/hip_fp16.h>
#include <math.h>

#define B_SZ 64
#define T_SZ 512
#define E_SZ 300
#define M_TOT (B_SZ * T_SZ)   // 32768 tokens
#define HSTR  152             // row stride (uints) of packed-f16x2 buffers (304 halves)

typedef _Float16 f16x8 __attribute__((ext_vector_type(8)));
typedef float    f32x4 __attribute__((ext_vector_type(4)));
typedef _Float16 h2_t  __attribute__((ext_vector_type(2)));

// f16-pair dot with fp32 accumulate
__device__ __forceinline__ float dot2(unsigned int a, unsigned int b, float c) {
#if __has_builtin(__builtin_amdgcn_fdot2)
    h2_t ah = __builtin_bit_cast(h2_t, a);
    h2_t bh = __builtin_bit_cast(h2_t, b);
    return __builtin_amdgcn_fdot2(ah, bh, c, false);
#else
    __half2 ah = __builtin_bit_cast(__half2, a);
    __half2 bh = __builtin_bit_cast(__half2, b);
    return c + __low2float(ah) * __low2float(bh) + __high2float(ah) * __high2float(bh);
#endif
}

__device__ __forceinline__ unsigned int packrte(float a, float b) {
    __half2 h = __floats2half2_rn(a, b);
    return __builtin_bit_cast(unsigned int, h);
}

// =====================================================================
// W fp32 -> packed f16x2, K padded to 320 halves (160 uints), zero tail.
// grid (300, 3), 160 threads. Wh layout: [mat][300][160 uints]
// =====================================================================
__global__ __launch_bounds__(160) void wconv(
    const float* __restrict__ fc1_w, const float* __restrict__ l1_w,
    const float* __restrict__ l2_w, unsigned int* __restrict__ Wh)
{
    const int r = blockIdx.x, m = blockIdx.y, j = threadIdx.x;
    const float* src; int stride;
    if (m == 0)      { src = fc1_w; stride = 300; }
    else if (m == 1) { src = l1_w;  stride = 600; }   // x-part cols 0..299
    else             { src = l2_w;  stride = 300; }
    int k = 2 * j;
    float a = (k < 300) ? src[(long)r * stride + k]     : 0.f;
    float b = (k < 300) ? src[(long)r * stride + k + 1] : 0.f;  // 300 even
    Wh[((long)m * 300 + r) * 160 + j] = packrte(a, b);
}

// =====================================================================
// MFMA GEMM: C[M,300] = A[M,300] @ W.T + bias  (f16 inputs, fp32 acc)
// Block tile 64(M) x 160(N), K-chunks of 32 (10 chunks, K padded to 320).
// 256 threads = 4 waves; wave w owns rows 16w..16w+15, all 10 n-frags.
// GATHER: A row m = emb[idx[m]] fp32 (convert in staging).
// else:   A = packed f16 [M][152 uints].
// OMODE: 0 = +bias, fp32 store;  1 = +bias, relu, f16 store (+pad zeros);
//        2 = +bias, max over 64 rows -> part[bx*320 + n]
// =====================================================================
template<bool GATHER, int OMODE>
__global__ __launch_bounds__(256) void mfma_gemm(
    const float* __restrict__ embA, const unsigned int* __restrict__ Ah,
    const int* __restrict__ idx,
    const unsigned int* __restrict__ Wh,   // [300][160] packed f16x2
    const float* __restrict__ bias,
    float* __restrict__ Cf, __half* __restrict__ Chh)
{
    __shared__ _Float16 At[64 * 40];    // row stride 40 halves (80 B)
    __shared__ _Float16 Bt[160 * 40];
    __shared__ float red[4][160];

    const int tid  = threadIdx.x;
    const int m0   = blockIdx.x * 64;
    const int n0   = blockIdx.y * 160;
    const int w    = tid >> 6;
    const int lane = tid & 63;
    const int ml   = lane & 15;
    const int q    = lane >> 4;

    const int ar = tid >> 2, ap = tid & 3;
    const float*        embrow = nullptr;
    const unsigned int* arow   = nullptr;
    if (GATHER) embrow = embA + (long)idx[m0 + ar] * 300;
    else        arow   = Ah + (long)(m0 + ar) * HSTR;

    f32x4 acc[10];
    #pragma unroll
    for (int i = 0; i < 10; i++) acc[i] = (f32x4){0.f, 0.f, 0.f, 0.f};

    #pragma unroll 1
    for (int kc = 0; kc < 10; kc++) {
        uint4 aval;
        if (GATHER) {
            int k = kc * 32 + ap * 8;
            float4 f0 = (k < 300)     ? *(const float4*)(embrow + k)     : make_float4(0,0,0,0);
            float4 f1 = (k + 4 < 300) ? *(const float4*)(embrow + k + 4) : make_float4(0,0,0,0);
            aval = make_uint4(packrte(f0.x, f0.y), packrte(f0.z, f0.w),
                              packrte(f1.x, f1.y), packrte(f1.z, f1.w));
        } else {
            int u = kc * 16 + ap * 4;
            aval = (u <= 148) ? *(const uint4*)(arow + u) : make_uint4(0, 0, 0, 0);
        }
        uint4 bval[3];
        #pragma unroll
        for (int jj = 0; jj < 3; jj++) {
            int i = tid + jj * 256;
            if (i < 640) {
                int row = i >> 2, quad = i & 3;
                int n = n0 + row;
                bval[jj] = (n < 300)
                    ? *(const uint4*)(Wh + (long)n * 160 + kc * 16 + quad * 4)
                    : make_uint4(0, 0, 0, 0);
            }
        }
        __syncthreads();
        *(uint4*)&At[ar * 40 + ap * 8] = aval;
        #pragma unroll
        for (int jj = 0; jj < 3; jj++) {
            int i = tid + jj * 256;
            if (i < 640) {
                int row = i >> 2, quad = i & 3;
                *(uint4*)&Bt[row * 40 + quad * 8] = bval[jj];
            }
        }
        __syncthreads();

        f16x8 af = *(const f16x8*)&At[(16 * w + ml) * 40 + q * 8];
        #pragma unroll
        for (int fi = 0; fi < 10; fi++) {
            f16x8 bf = *(const f16x8*)&Bt[(fi * 16 + ml) * 40 + q * 8];
            acc[fi] = __builtin_amdgcn_mfma_f32_16x16x32_f16(af, bf, acc[fi], 0, 0, 0);
        }
    }

    if (OMODE == 0 || OMODE == 1) {
        #pragma unroll
        for (int fi = 0; fi < 10; fi++) {
            int col = n0 + fi * 16 + ml;
            float bv = (col < 300) ? bias[col] : 0.f;
            #pragma unroll
            for (int r = 0; r < 4; r++) {
                long m = m0 + 16 * w + q * 4 + r;
                float v = acc[fi][r] + bv;
                if (OMODE == 0) {
                    if (col < 300) Cf[m * 300 + col] = v;
                } else {
                    if (col < 300)      Chh[m * 304 + col] = __float2half_rn(fmaxf(v, 0.f));
                    else if (col < 304) Chh[m * 304 + col] = __float2half_rn(0.f);
                }
            }
        }
    } else {
        #pragma unroll
        for (int fi = 0; fi < 10; fi++) {
            float v = fmaxf(fmaxf(acc[fi][0], acc[fi][1]), fmaxf(acc[fi][2], acc[fi][3]));
            v = fmaxf(v, __shfl_xor(v, 16));
            v = fmaxf(v, __shfl_xor(v, 32));
            if (lane < 16) red[w][fi * 16 + lane] = v;
        }
        __syncthreads();
        if (tid < 160) {
            int col = n0 + tid;
            if (col < 300) {
                float v = fmaxf(fmaxf(red[0][tid], red[1][tid]),
                                fmaxf(red[2][tid], red[3][tid]));
                Cf[(long)blockIdx.x * 320 + col] = v + bias[col];
            }
        }
    }
}

// =====================================================================
// RNN v6: v3's two-phase structure with VMEM issue moved to phase A.
// One block (512 thr) per batch element.
// Phase A: threads<300 issue (a) global store of h(t-1) from a register
//   stash and (b) xp prefetch for t+1 -- both retire during the ~600-cycle
//   dot phase, so barrier-1's vmcnt drain is ~free. Threads<450 do the
//   dot work: thread (g,s) owns outputs 4g..4g+3 over k-halves
//   [50s,50s+50), 100 weight uints in regs, broadcast LDS h reads,
//   one float4 partial write.
// Phase B: threads<300 reduce 6 partials, sigmoid, write h to LDS,
//   stash f16 for next phase A. NO VMEM in phase B -> barrier-2 drains
//   only LDS.
// =====================================================================
__global__ __launch_bounds__(512) void rnn_v6(
    const float* __restrict__ xpart,        // [B, T, 300] fp32
    const float* __restrict__ l1_w,         // [300, 600] fp32
    unsigned int* __restrict__ hid_out)     // [B, T, HSTR] packed f16x2
{
    const int b   = blockIdx.x;
    const int tid = threadIdx.x;

    // h slices: slice s at uints [28s, 28s+25): pair i = (h[50s+2i], h[50s+2i+1])
    __shared__ unsigned int hidh2[6 * 28];     // 168 uints
    __shared__ float partial[6][304];

    const bool dotact = (tid < 450);
    const int g = tid % 75;
    const int s = tid / 75;

    // ---- weight preload: wq[o][i] = packed (W[4g+o][300+50s+2i], +2i+1)
    unsigned int wq[4][25];
    if (dotact) {
        #pragma unroll
        for (int o = 0; o < 4; o++) {
            const float2* wr = (const float2*)(l1_w + (long)(4 * g + o) * 600 + 300 + 50 * s);
            #pragma unroll
            for (int i = 0; i < 25; i++) {
                float2 f = wr[i];
                wq[o][i] = packrte(f.x, f.y);
            }
        }
    }

    const bool redact = (tid < 300);
    const long xb = (long)b * T_SZ * 300;
    __half* gouth = (__half*)(hid_out + (long)b * T_SZ * HSTR);

    float xp_cur = 0.f;
    if (redact) xp_cur = xpart[xb + tid];   // t=0 additive term
    __half hh_prev = __float2half_rn(0.f);

    if (tid < 168) hidh2[tid] = 0u;         // hidden0 = zeros
    __syncthreads();

    #pragma unroll 1
    for (int t = 0; t < T_SZ; t++) {
        // ---------- phase A ----------
        float xp_next = 0.f;
        if (redact) {
            if (t > 0)
                gouth[(long)(t - 1) * 304 + tid] = hh_prev;   // retire during dot
            int tn = (t + 1 < T_SZ) ? t + 1 : t;
            xp_next = xpart[xb + (long)tn * 300 + tid];       // retire during dot
        }

        if (dotact) {
            const uint4* hv = (const uint4*)&hidh2[28 * s];
            const unsigned int hlast = hidh2[28 * s + 24];
            float a0 = 0.f, a1 = 0.f, a2 = 0.f, a3 = 0.f;
            #pragma unroll
            for (int i = 0; i < 6; i++) {
                uint4 h4 = hv[i];
                a0 = dot2(wq[0][4 * i + 0], h4.x, a0);
                a1 = dot2(wq[1][4 * i + 0], h4.x, a1);
                a2 = dot2(wq[2][4 * i + 0], h4.x, a2);
                a3 = dot2(wq[3][4 * i + 0], h4.x, a3);
                a0 = dot2(wq[0][4 * i + 1], h4.y, a0);
                a1 = dot2(wq[1][4 * i + 1], h4.y, a1);
                a2 = dot2(wq[2][4 * i + 1], h4.y, a2);
                a3 = dot2(wq[3][4 * i + 1], h4.y, a3);
                a0 = dot2(wq[0][4 * i + 2], h4.z, a0);
                a1 = dot2(wq[1][4 * i + 2], h4.z, a1);
                a2 = dot2(wq[2][4 * i + 2], h4.z, a2);
                a3 = dot2(wq[3][4 * i + 2], h4.z, a3);
                a0 = dot2(wq[0][4 * i + 3], h4.w, a0);
                a1 = dot2(wq[1][4 * i + 3], h4.w, a1);
                a2 = dot2(wq[2][4 * i + 3], h4.w, a2);
                a3 = dot2(wq[3][4 * i + 3], h4.w, a3);
            }
            a0 = dot2(wq[0][24], hlast, a0);
            a1 = dot2(wq[1][24], hlast, a1);
            a2 = dot2(wq[2][24], hlast, a2);
            a3 = dot2(wq[3][24], hlast, a3);
            *(float4*)&partial[s][4 * g] = make_float4(a0, a1, a2, a3);
        }
        __syncthreads();

        // ---------- phase B (no VMEM) ----------
        if (redact) {
            float y = xp_cur
                + ((partial[0][tid] + partial[1][tid]) + (partial[2][tid] + partial[3][tid]))
                + (partial[4][tid] + partial[5][tid]);
            float h = 1.f / (1.f + __expf(-y));
            __half hh = __float2half_rn(h);
            ((__half*)hidh2)[(tid / 50) * 56 + (tid % 50)] = hh;
            hh_prev = hh;
            xp_cur = xp_next;
        }
        __syncthreads();
    }

    // final step's h store
    if (redact) gouth[(long)(T_SZ - 1) * 304 + tid] = hh_prev;
}

// =====================================================================
// Final: pooled[b,n] = max over 8 m-chunks of part; out = pooled @ fc2_w.T
// =====================================================================
__global__ __launch_bounds__(320) void fc2_final(
    const float* __restrict__ part,     // [512, 320]
    const float* __restrict__ fc2_w,
    const float* __restrict__ fc2_b,
    float* __restrict__ out)
{
    const int b   = blockIdx.x;
    const int tid = threadIdx.x;
    __shared__ float pooled[304];

    if (tid < 300) {
        float m = part[(long)(b * 8) * 320 + tid];
        #pragma unroll
        for (int c = 1; c < 8; c++)
            m = fmaxf(m, part[(long)(b * 8 + c) * 320 + tid]);
        pooled[tid] = m;
    }
    __syncthreads();

    const int o    = tid >> 6;
    const int lane = tid & 63;
    if (o < 2) {
        float sacc = 0.f;
        for (int jj = lane; jj < 300; jj += 64)
            sacc += pooled[jj] * fc2_w[o * 300 + jj];
        #pragma unroll
        for (int off = 32; off > 0; off >>= 1)
            sacc += __shfl_down(sacc, off);
        if (lane == 0) out[b * 2 + o] = sacc + fc2_b[o];
    }
}

// =====================================================================
extern "C" void kernel_launch(void* const* d_in, const int* in_sizes, int n_in,
                              void* d_out, int out_size, void* d_ws, size_t ws_size,
                              hipStream_t stream)
{
    const int*   x     = (const int*)  d_in[0];
    const float* emb   = (const float*)d_in[1];
    const float* fc1_w = (const float*)d_in[2];
    const float* fc1_b = (const float*)d_in[3];
    const float* l1_w  = (const float*)d_in[4];
    const float* l1_b  = (const float*)d_in[5];
    const float* l2_w  = (const float*)d_in[6];
    const float* l2_b  = (const float*)d_in[7];
    const float* fc2_w = (const float*)d_in[8];
    const float* fc2_b = (const float*)d_in[9];
    float* out = (float*)d_out;

    // ws layout: bufH (19.9 MB) | bufX (39.3 MB) | part (0.66 MB) | Wh (0.58 MB)
    unsigned int* bufH = (unsigned int*)d_ws;
    float* bufX = (float*)(bufH + (size_t)M_TOT * HSTR);
    float* part = bufX + (size_t)M_TOT * 300;
    unsigned int* WhAll = (unsigned int*)(part + (size_t)512 * 320);
    unsigned int* W1h = WhAll;
    unsigned int* W2h = WhAll + (size_t)300 * 160;
    unsigned int* W3h = WhAll + (size_t)2 * 300 * 160;

    // K0: weights fp32 -> f16, K padded to 320
    wconv<<<dim3(300, 3), 160, 0, stream>>>(fc1_w, l1_w, l2_w, WhAll);
    // K1: h = relu(emb[x] @ fc1_w.T + fc1_b) -> packed f16 (pads zeroed)
    mfma_gemm<true, 1><<<dim3(512, 2), 256, 0, stream>>>(
        emb, nullptr, x, W1h, fc1_b, nullptr, (__half*)bufH);
    // K2: xpart = h @ l1_w[:, :300].T + l1_b -> fp32
    mfma_gemm<false, 0><<<dim3(512, 2), 256, 0, stream>>>(
        nullptr, bufH, nullptr, W2h, l1_b, bufX, nullptr);
    // K3: sequential RNN -> packed hiddens (overwrites bufH)
    rnn_v6<<<B_SZ, 512, 0, stream>>>(bufX, l1_w, bufH);
    // K4: outs = hid @ l2_w.T + l2_b, fused 64-row max -> part
    mfma_gemm<false, 2><<<dim3(512, 2), 256, 0, stream>>>(
        nullptr, bufH, nullptr, W3h, l2_b, part, nullptr);
    // K5: final max over chunks + fc2
    fc2_final<<<B_SZ, 320, 0, stream>>>(part, fc2_w, fc2_b, out);
}

// Round 7
// 509.255 us; speedup vs baseline: 1.5266x; 1.1853x over previous
//
#include <hip/hip_runtime.h>
#include <hip/hip_fp16.h>
#include <math.h>

#define B_SZ 64
#define T_SZ 512
#define M_TOT (B_SZ * T_SZ)   // 32768 tokens
#define HSTR  160             // uints per row (320 halves; cols 300..319 zero)
#define NPASS 11              // GEMM refinement passes (total steps = NPASS+1)

typedef _Float16 f16x8 __attribute__((ext_vector_type(8)));
typedef float    f32x4 __attribute__((ext_vector_type(4)));

__device__ __forceinline__ unsigned int packrte(float a, float b) {
    __half2 h = __floats2half2_rn(a, b);
    return __builtin_bit_cast(unsigned int, h);
}

// =====================================================================
// Weights fp32 -> packed f16x2 rows of HSTR uints (zero-padded K).
// grid (300, 4): m=0 fc1_w, m=1 l1_w x-part, m=2 l2_w, m=3 l1_w h-part.
// =====================================================================
__global__ __launch_bounds__(160) void wconv(
    const float* __restrict__ fc1_w, const float* __restrict__ l1_w,
    const float* __restrict__ l2_w, unsigned int* __restrict__ Wh)
{
    const int r = blockIdx.x, m = blockIdx.y, j = threadIdx.x;
    const float* src; int stride, off;
    if (m == 0)      { src = fc1_w; stride = 300; off = 0; }
    else if (m == 1) { src = l1_w;  stride = 600; off = 0; }
    else if (m == 2) { src = l2_w;  stride = 300; off = 0; }
    else             { src = l1_w;  stride = 600; off = 300; }
    int k = 2 * j;
    float a = (k < 300) ? src[(long)r * stride + off + k]     : 0.f;
    float b = (k < 300) ? src[(long)r * stride + off + k + 1] : 0.f;
    Wh[((long)m * 300 + r) * HSTR + j] = packrte(a, b);
}

// =====================================================================
// Unified MFMA GEMM: C[M,300] = f(A[M,300] @ W.T).  f16 in, fp32 acc.
// Tile 64(M) x 160(N), 10 K-chunks of 32, 256 thr (4 waves), register
// prefetch double-buffering (chunk k+1 loads issued under chunk k MFMA).
// AMODE: 0 = gather emb fp32 rows via idx (pack f16 in staging)
//        1 = f16 rows Ah[M][HSTR]
//        2 = f16 rows shifted -1 in time (zero at t%512==0 rows)
// OMODE: 0 = +bias (+RELU) -> f16 store (pads zeroed)
//        1 = +xpart(f16), sigmoid -> f16 store (pads zeroed)
//        2 = +bias after 64-row column max -> part[bx*320+n]
// =====================================================================
template<int AMODE, int OMODE, bool RELU>
__global__ __launch_bounds__(256) void gemmx(
    const float* __restrict__ embA, const int* __restrict__ idx,
    const unsigned int* __restrict__ Ah,
    const unsigned int* __restrict__ Wm,    // [300][HSTR]
    const float* __restrict__ bias,
    const unsigned int* __restrict__ Xp,    // OMODE1: xpart f16 [M][HSTR]
    unsigned int* __restrict__ Ch,          // f16 out rows [M][HSTR]
    float* __restrict__ Cf)                 // OMODE2: part
{
    __shared__ _Float16 At[64 * 40];    // row stride 40 halves
    __shared__ _Float16 Bt[160 * 40];
    __shared__ float red[4][160];

    const int tid  = threadIdx.x;
    const int m0   = blockIdx.x * 64;
    const int n0   = blockIdx.y * 160;
    const int w    = tid >> 6;
    const int lane = tid & 63;
    const int ml   = lane & 15;
    const int q    = lane >> 4;

    const int ar = tid >> 2, ap = tid & 3;   // staging: row, 8-half part

    const float*        embrow = nullptr;
    const unsigned int* arow   = nullptr;
    bool a_zero = false;
    if (AMODE == 0) {
        embrow = embA + (long)idx[m0 + ar] * 300;
    } else if (AMODE == 1) {
        arow = Ah + (long)(m0 + ar) * HSTR;
    } else {
        a_zero = ((m0 + ar) & (T_SZ - 1)) == 0;   // t==0 rows read h(-1)=0
        arow = Ah + (long)(m0 + ar - 1) * HSTR;
    }

    uint4 aval;
    uint4 bval[3];

    auto loadA = [&](int kc) {
        if (AMODE == 0) {
            int k = kc * 32 + ap * 8;
            float4 f0 = (k + 4 <= 300) ? *(const float4*)(embrow + k)     : make_float4(0,0,0,0);
            float4 f1 = (k + 8 <= 300) ? *(const float4*)(embrow + k + 4) : make_float4(0,0,0,0);
            aval = make_uint4(packrte(f0.x, f0.y), packrte(f0.z, f0.w),
                              packrte(f1.x, f1.y), packrte(f1.z, f1.w));
        } else if (AMODE == 1) {
            aval = *(const uint4*)(arow + kc * 16 + ap * 4);
        } else {
            aval = a_zero ? make_uint4(0, 0, 0, 0)
                          : *(const uint4*)(arow + kc * 16 + ap * 4);
        }
    };
    auto loadB = [&](int kc) {
        #pragma unroll
        for (int jj = 0; jj < 3; jj++) {
            int i = tid + jj * 256;
            if (i < 640) {
                int row = i >> 2, quad = i & 3;
                int n = n0 + row;
                bval[jj] = (n < 300)
                    ? *(const uint4*)(Wm + (long)n * HSTR + kc * 16 + quad * 4)
                    : make_uint4(0, 0, 0, 0);
            }
        }
    };

    loadA(0);
    loadB(0);

    f32x4 acc[10];
    #pragma unroll
    for (int i = 0; i < 10; i++) acc[i] = (f32x4){0.f, 0.f, 0.f, 0.f};

    #pragma unroll 1
    for (int kc = 0; kc < 10; kc++) {
        __syncthreads();                          // prev chunk frag reads done
        *(uint4*)&At[ar * 40 + ap * 8] = aval;
        #pragma unroll
        for (int jj = 0; jj < 3; jj++) {
            int i = tid + jj * 256;
            if (i < 640) *(uint4*)&Bt[(i >> 2) * 40 + (i & 3) * 8] = bval[jj];
        }
        __syncthreads();
        if (kc < 9) { loadA(kc + 1); loadB(kc + 1); }   // retire under MFMA

        f16x8 af = *(const f16x8*)&At[(16 * w + ml) * 40 + q * 8];
        #pragma unroll
        for (int fi = 0; fi < 10; fi++) {
            f16x8 bf = *(const f16x8*)&Bt[(fi * 16 + ml) * 40 + q * 8];
            acc[fi] = __builtin_amdgcn_mfma_f32_16x16x32_f16(af, bf, acc[fi], 0, 0, 0);
        }
    }

    // ---- epilogue. D: row m = m0+16w+q*4+r, col n = n0+fi*16+ml
    if (OMODE == 2) {
        #pragma unroll
        for (int fi = 0; fi < 10; fi++) {
            float v = fmaxf(fmaxf(acc[fi][0], acc[fi][1]), fmaxf(acc[fi][2], acc[fi][3]));
            v = fmaxf(v, __shfl_xor(v, 16));
            v = fmaxf(v, __shfl_xor(v, 32));
            if (lane < 16) red[w][fi * 16 + lane] = v;
        }
        __syncthreads();
        if (tid < 160) {
            int col = n0 + tid;
            if (col < 300) {
                float v = fmaxf(fmaxf(red[0][tid], red[1][tid]),
                                fmaxf(red[2][tid], red[3][tid]));
                Cf[(long)blockIdx.x * 320 + col] = v + bias[col];
            }
        }
    } else {
        unsigned short* outh = (unsigned short*)Ch;
        const __half* xph = (const __half*)Xp;
        #pragma unroll
        for (int fi = 0; fi < 10; fi++) {
            int col = n0 + fi * 16 + ml;
            float bv = (OMODE == 0 && col < 300) ? bias[col] : 0.f;
            #pragma unroll
            for (int r = 0; r < 4; r++) {
                long m = m0 + 16 * w + q * 4 + r;
                unsigned short st = 0;
                if (col < 300) {
                    float v = acc[fi][r];
                    if (OMODE == 0) {
                        v += bv;
                        if (RELU) v = fmaxf(v, 0.f);
                    } else {
                        v += __half2float(xph[m * 320 + col]);
                        v = 1.f / (1.f + __expf(-v));
                    }
                    __half hv = __float2half_rn(v);
                    st = __builtin_bit_cast(unsigned short, hv);
                }
                outh[m * 320 + col] = st;   // pads -> 0
            }
        }
    }
}

// =====================================================================
// Pass 0: G_1 = sigmoid(xpart) elementwise (pads stay 0).
// =====================================================================
__global__ __launch_bounds__(256) void pass0(
    const unsigned int* __restrict__ Xp, unsigned int* __restrict__ G)
{
    long i = (long)blockIdx.x * 256 + threadIdx.x;
    int u = (int)(i % HSTR);
    unsigned int xv = Xp[i];
    unsigned int o = 0;
    if (u < 150) {
        __half2 h2 = __builtin_bit_cast(__half2, xv);
        float a = 1.f / (1.f + __expf(-__low2float(h2)));
        float b = 1.f / (1.f + __expf(-__high2float(h2)));
        o = packrte(a, b);
    }
    G[i] = o;
}

// =====================================================================
// Final: pooled[b,n] = max over 8 m-chunks of part; out = pooled @ fc2_w.T
// =====================================================================
__global__ __launch_bounds__(320) void fc2_final(
    const float* __restrict__ part,     // [512, 320]
    const float* __restrict__ fc2_w,
    const float* __restrict__ fc2_b,
    float* __restrict__ out)
{
    const int b   = blockIdx.x;
    const int tid = threadIdx.x;
    __shared__ float pooled[304];

    if (tid < 300) {
        float m = part[(long)(b * 8) * 320 + tid];
        #pragma unroll
        for (int c = 1; c < 8; c++)
            m = fmaxf(m, part[(long)(b * 8 + c) * 320 + tid]);
        pooled[tid] = m;
    }
    __syncthreads();

    const int o    = tid >> 6;
    const int lane = tid & 63;
    if (o < 2) {
        float sacc = 0.f;
        for (int jj = lane; jj < 300; jj += 64)
            sacc += pooled[jj] * fc2_w[o * 300 + jj];
        #pragma unroll
        for (int off = 32; off > 0; off >>= 1)
            sacc += __shfl_down(sacc, off);
        if (lane == 0) out[b * 2 + o] = sacc + fc2_b[o];
    }
}

// =====================================================================
extern "C" void kernel_launch(void* const* d_in, const int* in_sizes, int n_in,
                              void* d_out, int out_size, void* d_ws, size_t ws_size,
                              hipStream_t stream)
{
    const int*   x     = (const int*)  d_in[0];
    const float* emb   = (const float*)d_in[1];
    const float* fc1_w = (const float*)d_in[2];
    const float* fc1_b = (const float*)d_in[3];
    const float* l1_w  = (const float*)d_in[4];
    const float* l1_b  = (const float*)d_in[5];
    const float* l2_w  = (const float*)d_in[6];
    const float* l2_b  = (const float*)d_in[7];
    const float* fc2_w = (const float*)d_in[8];
    const float* fc2_b = (const float*)d_in[9];
    float* out = (float*)d_out;

    // ws: Gb (21MB, also h) | Xp (21MB) | Ga (21MB) | part | Wh  (~64.5MB)
    unsigned int* Gb = (unsigned int*)d_ws;
    unsigned int* Xp = Gb + (size_t)M_TOT * HSTR;
    unsigned int* Ga = Xp + (size_t)M_TOT * HSTR;
    float* part = (float*)(Ga + (size_t)M_TOT * HSTR);
    unsigned int* Wh = (unsigned int*)(part + (size_t)512 * 320);
    unsigned int* W1  = Wh;                               // fc1
    unsigned int* W2x = Wh + (size_t)300 * HSTR;          // l1 x-part
    unsigned int* W3  = Wh + (size_t)2 * 300 * HSTR;      // l2
    unsigned int* Whh = Wh + (size_t)3 * 300 * HSTR;      // l1 h-part

    dim3 gg(M_TOT / 64, 2), gb(256);

    // K0: all weights -> f16 padded rows
    wconv<<<dim3(300, 4), 160, 0, stream>>>(fc1_w, l1_w, l2_w, Wh);
    // K1: h = relu(emb[x] @ fc1_w.T + fc1_b) -> f16 (into Gb, dead after K2)
    gemmx<0, 0, true><<<gg, gb, 0, stream>>>(
        emb, x, nullptr, W1, fc1_b, nullptr, Gb, nullptr);
    // K2: xpart = h @ l1_wx.T + l1_b -> f16
    gemmx<1, 0, false><<<gg, gb, 0, stream>>>(
        nullptr, nullptr, Gb, W2x, l1_b, nullptr, Xp, nullptr);
    // P0: G = sigmoid(xpart)
    pass0<<<(M_TOT * HSTR) / 256, 256, 0, stream>>>(Xp, Ga);
    // Fixed-point refinement: G <- sigmoid(xpart + shift(G) @ Whh.T)
    for (int p = 0; p < NPASS; p++) {
        const unsigned int* src = (p & 1) ? Gb : Ga;
        unsigned int*       dst = (p & 1) ? Ga : Gb;
        gemmx<2, 1, false><<<gg, gb, 0, stream>>>(
            nullptr, nullptr, src, Whh, nullptr, Xp, dst, nullptr);
    }
    // NPASS=11 (odd) -> final hidden states in Gb
    // K4: outs = hid @ l2_w.T + l2_b, fused 64-row max -> part
    gemmx<1, 2, false><<<gg, gb, 0, stream>>>(
        nullptr, nullptr, Gb, W3, l2_b, nullptr, nullptr, part);
    // K5: final max over chunks + fc2
    fc2_final<<<B_SZ, 320, 0, stream>>>(part, fc2_w, fc2_b, out);
}